// Round 5
// baseline (2362.166 us; speedup 1.0000x reference)
//
#include <hip/hip_runtime.h>

#define INF 256
#define OUTF 128
#define NBMAX 1024        // max coarse buckets (row>>7 -> 782 for N=100000)
#define BUCKET_CAP 4608   // per-bucket capacity: mean 4092, std 64 -> +8 sigma

typedef _Float16 half2v __attribute__((ext_vector_type(2)));
typedef _Float16 half8 __attribute__((ext_vector_type(8)));
typedef float f32x4 __attribute__((ext_vector_type(4)));

__device__ inline unsigned short f16bits(float v) {
    union { unsigned short u; _Float16 h; } cv;
    cv.h = (_Float16)v;
    return cv.u;
}
__device__ inline float f16val15(unsigned rec) {
    union { unsigned short u; _Float16 h; } cv;
    cv.u = (unsigned short)(rec << 1);
    return (float)cv.h;
}

// ---------------------------------------------------------------------------
// Prepack W into MFMA B-fragment order (f16) + init bucket cursors.
// ---------------------------------------------------------------------------
__global__ __launch_bounds__(256) void k_prepack(const float* __restrict__ w,
                                                 _Float16* __restrict__ wpack,
                                                 int* __restrict__ bcursor,
                                                 int NB) {
    int t = blockIdx.x * 256 + threadIdx.x;   // 32768 threads
    int k = t >> 7, n = t & 127;
    int ks = k >> 5, quad = (k >> 3) & 3, j = k & 7;
    int ct = n >> 4, nn = n & 15;
    wpack[(((ks * 8 + ct) * 4 + quad) * 16 + nn) * 8 + j] = (_Float16)w[k * OUTF + n];
    if (t < NB) bcursor[t] = t * BUCKET_CAP;
}

// ---------------------------------------------------------------------------
// MFMA GEMM: support = x @ w via 16x16x32 f16 MFMA, no LDS.
// Output in SLAB-MAJOR layout: support[slice(ct)][row][16 feats] f16,
// so each 16-feature slab (3.2 MB) is contiguous and per-XCD-L2-resident.
// ---------------------------------------------------------------------------
__global__ __launch_bounds__(256) void gcn_gemm_mfma(const float* __restrict__ x,
                                                     const _Float16* __restrict__ wpack,
                                                     _Float16* __restrict__ support,
                                                     int N) {
    const int tid = threadIdx.x;
    const int wv = tid >> 6;
    const int lane = tid & 63;
    const int m16 = lane & 15;
    const int quad = lane >> 4;
    const int rowbase = blockIdx.x * 128 + wv * 32;

    f32x4 acc[2][8];
#pragma unroll
    for (int rt = 0; rt < 2; ++rt)
#pragma unroll
        for (int ct = 0; ct < 8; ++ct)
            acc[rt][ct] = (f32x4){0.f, 0.f, 0.f, 0.f};

    int r0 = rowbase + m16;
    int r1 = rowbase + 16 + m16;
    int r0c = (r0 < N) ? r0 : N - 1;
    int r1c = (r1 < N) ? r1 : N - 1;
    const float* xr0 = x + (long)r0c * INF + quad * 8;
    const float* xr1 = x + (long)r1c * INF + quad * 8;

    for (int ks = 0; ks < 8; ++ks) {
        float4 u0 = *(const float4*)(xr0 + ks * 32);
        float4 v0 = *(const float4*)(xr0 + ks * 32 + 4);
        float4 u1 = *(const float4*)(xr1 + ks * 32);
        float4 v1 = *(const float4*)(xr1 + ks * 32 + 4);
        half8 a0 = {(_Float16)u0.x, (_Float16)u0.y, (_Float16)u0.z, (_Float16)u0.w,
                    (_Float16)v0.x, (_Float16)v0.y, (_Float16)v0.z, (_Float16)v0.w};
        half8 a1 = {(_Float16)u1.x, (_Float16)u1.y, (_Float16)u1.z, (_Float16)u1.w,
                    (_Float16)v1.x, (_Float16)v1.y, (_Float16)v1.z, (_Float16)v1.w};

        half8 b[8];
#pragma unroll
        for (int ct = 0; ct < 8; ++ct)
            b[ct] = *(const half8*)(wpack + (size_t)(((ks * 8 + ct) * 4 + quad) * 16 + m16) * 8);

#pragma unroll
        for (int ct = 0; ct < 8; ++ct) {
            acc[0][ct] = __builtin_amdgcn_mfma_f32_16x16x32_f16(a0, b[ct], acc[0][ct], 0, 0, 0);
            acc[1][ct] = __builtin_amdgcn_mfma_f32_16x16x32_f16(a1, b[ct], acc[1][ct], 0, 0, 0);
        }
    }

    // C/D layout: col = lane&15, row = quad*4 + reg. Slab-major store.
#pragma unroll
    for (int rt = 0; rt < 2; ++rt) {
        int rb = rowbase + rt * 16 + quad * 4;
#pragma unroll
        for (int reg = 0; reg < 4; ++reg) {
            int r = rb + reg;
            if (r < N) {
#pragma unroll
                for (int ct = 0; ct < 8; ++ct)
                    support[((size_t)ct * N + r) * 16 + m16] = (_Float16)acc[rt][ct][reg];
            }
        }
    }
}

// ---------------------------------------------------------------------------
// Coarse scatter: append records into fixed-capacity per-bucket regions.
// colval[pos] = col<<15 | f16(val)>>1   (4B),  lrowarr[pos] = row&127 (1B).
// Intra-bucket order irrelevant (gather accumulates via LDS tile).
// ---------------------------------------------------------------------------
__global__ __launch_bounds__(256) void k_coarse_scatter(const int* __restrict__ row,
                                                        const int* __restrict__ col,
                                                        const float* __restrict__ vals,
                                                        int* __restrict__ bcursor,
                                                        unsigned* __restrict__ colval,
                                                        unsigned char* __restrict__ lrowarr,
                                                        int NB, int E) {
    __shared__ int cnt[NBMAX];
    __shared__ int sbase[NBMAX];
    const int tid = threadIdx.x;
    for (int i = tid; i < NB; i += 256) cnt[i] = 0;
    __syncthreads();

    int rr[16], rk[16];
    unsigned rec[16];
    int base = blockIdx.x * 4096;
#pragma unroll
    for (int j = 0; j < 16; ++j) {
        int e = base + j * 256 + tid;
        if (e < E) {
            int r = row[e];
            rec[j] = ((unsigned)col[e] << 15) | ((unsigned)f16bits(vals[e]) >> 1);
            rr[j] = r;
            rk[j] = atomicAdd(&cnt[r >> 7], 1);
        } else {
            rr[j] = -1;
        }
    }
    __syncthreads();
    for (int i = tid; i < NB; i += 256) {
        int c = cnt[i];
        if (c) sbase[i] = atomicAdd(&bcursor[i], c);
    }
    __syncthreads();
#pragma unroll
    for (int j = 0; j < 16; ++j) {
        if (rr[j] >= 0) {
            int pos = sbase[rr[j] >> 7] + rk[j];
            colval[pos] = rec[j];
            lrowarr[pos] = (unsigned char)(rr[j] & 127);
        }
    }
}

// ---------------------------------------------------------------------------
// Gather: one block per (bucket, slice). blockIdx%8 = slice -> round-robin
// XCD mapping keeps each 3.2MB slab resident in one XCD's L2.
// Accumulate into LDS tile [128 rows][16 feats] (pad 17) via ds_add_f32,
// then write out-tile + bias coalesced.
// ---------------------------------------------------------------------------
__global__ __launch_bounds__(256) void k_gather_tile(const _Float16* __restrict__ slabs,
                                                     const unsigned* __restrict__ colval,
                                                     const unsigned char* __restrict__ lrowarr,
                                                     const int* __restrict__ bcursor,
                                                     const float* __restrict__ bias,
                                                     float* __restrict__ out,
                                                     int N) {
    __shared__ float tile[128][17];
    const int tid = threadIdx.x;
    const int b = blockIdx.x >> 3;
    const int g = blockIdx.x & 7;

    for (int i = tid; i < 128 * 17; i += 256) ((float*)tile)[i] = 0.f;

    const int start = b * BUCKET_CAP;
    const int n = bcursor[b] - start;
    const int wv = tid >> 6;
    const int lane = tid & 63;
    const int eslot = lane >> 3;
    const int fpair = lane & 7;
    const _Float16* slab = slabs + (size_t)g * N * 16;
    __syncthreads();

    for (int i = wv * 8 + eslot; i < n; i += 32) {
        unsigned rec = colval[start + i];
        int lr = lrowarr[start + i];
        float v = f16val15(rec);
        unsigned c = rec >> 15;
        half2v h = *(const half2v*)(slab + ((size_t)c * 8 + (unsigned)fpair) * 2);
        atomicAdd(&tile[lr][fpair * 2 + 0], v * (float)h.x);
        atomicAdd(&tile[lr][fpair * 2 + 1], v * (float)h.y);
    }
    __syncthreads();

    const int row0 = b << 7;
    for (int i = tid; i < 128 * 8; i += 256) {
        int r = i >> 3, fp = i & 7;
        int gr = row0 + r;
        if (gr < N) {
            float2 o;
            o.x = tile[r][fp * 2 + 0] + bias[g * 16 + fp * 2 + 0];
            o.y = tile[r][fp * 2 + 1] + bias[g * 16 + fp * 2 + 1];
            *(float2*)(out + (size_t)gr * OUTF + g * 16 + fp * 2) = o;
        }
    }
}

// ---------------------------------------------------------------------------
extern "C" void kernel_launch(void* const* d_in, const int* in_sizes, int n_in,
                              void* d_out, int out_size, void* d_ws, size_t ws_size,
                              hipStream_t stream) {
    const float* x    = (const float*)d_in[0];
    const float* vals = (const float*)d_in[1];
    const float* w    = (const float*)d_in[2];
    const float* bias = (const float*)d_in[3];
    const int*   row  = (const int*)d_in[4];
    const int*   col  = (const int*)d_in[5];

    const int N = in_sizes[0] / INF;   // 100000
    const int E = in_sizes[1];         // 3200000
    const int NB = (N + 127) / 128;    // 782 coarse buckets

    // ---- workspace carve-up ----
    char* p = (char*)d_ws;
    _Float16* support  = (_Float16*)p;      p += (size_t)N * OUTF * sizeof(_Float16);        // 25.6 MB
    unsigned* colval   = (unsigned*)p;      p += (size_t)NB * BUCKET_CAP * sizeof(unsigned); // 14.4 MB
    unsigned char* lrowarr = (unsigned char*)p; p += (size_t)NB * BUCKET_CAP;                // 3.6 MB
    _Float16* wpack    = (_Float16*)p;      p += (size_t)INF * OUTF * sizeof(_Float16);      // 64 KB
    int* bcursor       = (int*)p;           p += (size_t)NBMAX * sizeof(int);

    const int eb4096 = (E + 4095) / 4096;

    // 1) prepack W (f16 B-frag layout) + init bucket cursors
    k_prepack<<<(INF * OUTF) / 256, 256, 0, stream>>>(w, wpack, bcursor, NB);

    // 2) GEMM: support slabs = x @ w  via f16 MFMA
    gcn_gemm_mfma<<<(N + 127) / 128, 256, 0, stream>>>(x, wpack, support, N);

    // 3) partition edges into fixed-capacity coarse buckets (unsorted)
    k_coarse_scatter<<<eb4096, 256, 0, stream>>>(row, col, vals, bcursor,
                                                 colval, lrowarr, NB, E);

    // 4) gather: (bucket, slice) blocks, LDS tile accumulation, bias fused
    k_gather_tile<<<NB * 8, 256, 0, stream>>>(support, colval, lrowarr,
                                              bcursor, bias, (float*)d_out, N);
}

// Round 6
// 633.989 us; speedup vs baseline: 3.7259x; 3.7259x over previous
//
#include <hip/hip_runtime.h>

#define INF 256
#define OUTF 128
#define NBMAX 1024        // max coarse buckets (row>>7 -> 782 for N=100000)
#define BUCKET_CAP 4608   // per-bucket capacity: mean 4092, std 64 -> +8 sigma

typedef _Float16 half2v __attribute__((ext_vector_type(2)));
typedef _Float16 half8 __attribute__((ext_vector_type(8)));
typedef float f32x4 __attribute__((ext_vector_type(4)));

__device__ inline unsigned short f16bits(float v) {
    union { unsigned short u; _Float16 h; } cv;
    cv.h = (_Float16)v;
    return cv.u;
}
__device__ inline float f16val15(unsigned rec) {
    union { unsigned short u; _Float16 h; } cv;
    cv.u = (unsigned short)(rec << 1);
    return (float)cv.h;
}

// ---------------------------------------------------------------------------
// Prepack W into MFMA B-fragment order (f16) + init bucket cursors.
// ---------------------------------------------------------------------------
__global__ __launch_bounds__(256) void k_prepack(const float* __restrict__ w,
                                                 _Float16* __restrict__ wpack,
                                                 int* __restrict__ bcursor,
                                                 int NB) {
    int t = blockIdx.x * 256 + threadIdx.x;   // 32768 threads
    int k = t >> 7, n = t & 127;
    int ks = k >> 5, quad = (k >> 3) & 3, j = k & 7;
    int ct = n >> 4, nn = n & 15;
    wpack[(((ks * 8 + ct) * 4 + quad) * 16 + nn) * 8 + j] = (_Float16)w[k * OUTF + n];
    if (t < NB) bcursor[t] = t * BUCKET_CAP;
}

// ---------------------------------------------------------------------------
// MFMA GEMM: support = x @ w via 16x16x32 f16 MFMA, no LDS.
// Output SLAB-MAJOR: support[slab(ct)][row][16 feats] f16 (slab = 3.2 MB,
// per-XCD L2-resident for the gather).
// ---------------------------------------------------------------------------
__global__ __launch_bounds__(256) void gcn_gemm_mfma(const float* __restrict__ x,
                                                     const _Float16* __restrict__ wpack,
                                                     _Float16* __restrict__ support,
                                                     int N) {
    const int tid = threadIdx.x;
    const int wv = tid >> 6;
    const int lane = tid & 63;
    const int m16 = lane & 15;
    const int quad = lane >> 4;
    const int rowbase = blockIdx.x * 128 + wv * 32;

    f32x4 acc[2][8];
#pragma unroll
    for (int rt = 0; rt < 2; ++rt)
#pragma unroll
        for (int ct = 0; ct < 8; ++ct)
            acc[rt][ct] = (f32x4){0.f, 0.f, 0.f, 0.f};

    int r0 = rowbase + m16;
    int r1 = rowbase + 16 + m16;
    int r0c = (r0 < N) ? r0 : N - 1;
    int r1c = (r1 < N) ? r1 : N - 1;
    const float* xr0 = x + (long)r0c * INF + quad * 8;
    const float* xr1 = x + (long)r1c * INF + quad * 8;

    for (int ks = 0; ks < 8; ++ks) {
        float4 u0 = *(const float4*)(xr0 + ks * 32);
        float4 v0 = *(const float4*)(xr0 + ks * 32 + 4);
        float4 u1 = *(const float4*)(xr1 + ks * 32);
        float4 v1 = *(const float4*)(xr1 + ks * 32 + 4);
        half8 a0 = {(_Float16)u0.x, (_Float16)u0.y, (_Float16)u0.z, (_Float16)u0.w,
                    (_Float16)v0.x, (_Float16)v0.y, (_Float16)v0.z, (_Float16)v0.w};
        half8 a1 = {(_Float16)u1.x, (_Float16)u1.y, (_Float16)u1.z, (_Float16)u1.w,
                    (_Float16)v1.x, (_Float16)v1.y, (_Float16)v1.z, (_Float16)v1.w};

        half8 b[8];
#pragma unroll
        for (int ct = 0; ct < 8; ++ct)
            b[ct] = *(const half8*)(wpack + (size_t)(((ks * 8 + ct) * 4 + quad) * 16 + m16) * 8);

#pragma unroll
        for (int ct = 0; ct < 8; ++ct) {
            acc[0][ct] = __builtin_amdgcn_mfma_f32_16x16x32_f16(a0, b[ct], acc[0][ct], 0, 0, 0);
            acc[1][ct] = __builtin_amdgcn_mfma_f32_16x16x32_f16(a1, b[ct], acc[1][ct], 0, 0, 0);
        }
    }

    // C/D layout: col = lane&15, row = quad*4 + reg. Slab-major store.
#pragma unroll
    for (int rt = 0; rt < 2; ++rt) {
        int rb = rowbase + rt * 16 + quad * 4;
#pragma unroll
        for (int reg = 0; reg < 4; ++reg) {
            int r = rb + reg;
            if (r < N) {
#pragma unroll
                for (int ct = 0; ct < 8; ++ct)
                    support[((size_t)ct * N + r) * 16 + m16] = (_Float16)acc[rt][ct][reg];
            }
        }
    }
}

// ---------------------------------------------------------------------------
// Coarse scatter: append final-format records into fixed-capacity buckets.
// cv_tmp[pos] = col<<15 | f16(val)>>1 (4B), lr_tmp[pos] = row&127 (1B).
// ---------------------------------------------------------------------------
__global__ __launch_bounds__(256) void k_coarse_scatter(const int* __restrict__ row,
                                                        const int* __restrict__ col,
                                                        const float* __restrict__ vals,
                                                        int* __restrict__ bcursor,
                                                        unsigned* __restrict__ cv_tmp,
                                                        unsigned char* __restrict__ lr_tmp,
                                                        int NB, int E) {
    __shared__ int cnt[NBMAX];
    __shared__ int sbase[NBMAX];
    const int tid = threadIdx.x;
    for (int i = tid; i < NB; i += 256) cnt[i] = 0;
    __syncthreads();

    int rr[16], rk[16];
    unsigned rec[16];
    int base = blockIdx.x * 4096;
#pragma unroll
    for (int j = 0; j < 16; ++j) {
        int e = base + j * 256 + tid;
        if (e < E) {
            int r = row[e];
            rec[j] = ((unsigned)col[e] << 15) | ((unsigned)f16bits(vals[e]) >> 1);
            rr[j] = r;
            rk[j] = atomicAdd(&cnt[r >> 7], 1);
        } else {
            rr[j] = -1;
        }
    }
    __syncthreads();
    for (int i = tid; i < NB; i += 256) {
        int c = cnt[i];
        if (c) sbase[i] = atomicAdd(&bcursor[i], c);
    }
    __syncthreads();
#pragma unroll
    for (int j = 0; j < 16; ++j) {
        if (rr[j] >= 0) {
            int pos = sbase[rr[j] >> 7] + rk[j];
            cv_tmp[pos] = rec[j];
            lr_tmp[pos] = (unsigned char)(rr[j] & 127);
        }
    }
}

// ---------------------------------------------------------------------------
// Per-bucket counting sort: permute 4B records into per-row order + rs/re.
// ---------------------------------------------------------------------------
__global__ __launch_bounds__(256) void k_bucket_sort(const unsigned* __restrict__ cv_tmp,
                                                     const unsigned char* __restrict__ lr_tmp,
                                                     const int* __restrict__ bcursor,
                                                     unsigned* __restrict__ frecs,
                                                     int* __restrict__ rs,
                                                     int* __restrict__ re,
                                                     int N) {
    __shared__ unsigned recs[BUCKET_CAP];
    __shared__ unsigned char lrows[BUCKET_CAP];
    __shared__ int cnt[128];
    __shared__ int offs[128];

    const int tid = threadIdx.x;
    const int b = blockIdx.x;
    const int start = b * BUCKET_CAP;
    int n = bcursor[b] - start;
    if (n > BUCKET_CAP) n = BUCKET_CAP;
    const int row0 = b << 7;

    if (tid < 128) cnt[tid] = 0;
    __syncthreads();

    for (int i = tid; i < n; i += 256) {
        unsigned c = cv_tmp[start + i];
        unsigned char l = lr_tmp[start + i];
        recs[i] = c;
        lrows[i] = l;
        atomicAdd(&cnt[l], 1);
    }
    __syncthreads();

    if (tid < 128) offs[tid] = cnt[tid];
    __syncthreads();
    for (int d = 1; d < 128; d <<= 1) {
        int add = 0;
        if (tid < 128 && tid >= d) add = offs[tid - d];
        __syncthreads();
        if (tid < 128) offs[tid] += add;
        __syncthreads();
    }
    if (tid < 128) {
        int excl = offs[tid] - cnt[tid];
        offs[tid] = excl;                 // running cursor
        int r = row0 + tid;
        if (r < N) {
            rs[r] = start + excl;
            re[r] = start + excl + cnt[tid];
        }
    }
    __syncthreads();

    for (int i = tid; i < n; i += 256) {
        int l = lrows[i];
        int pos = atomicAdd(&offs[l], 1);
        frecs[start + pos] = recs[i];
    }
}

// ---------------------------------------------------------------------------
// Gather: block = (bucket, slab). blockIdx&7 = slab -> XCD-affine, slab
// (3.2 MB) stays L2-resident. Lane = (eslot 0..7, fpair 0..7): 8 edges in
// flight x 8 f16-pairs. Register accumulation + shfl reduction, no atomics.
// ---------------------------------------------------------------------------
__global__ __launch_bounds__(256) void k_gather_slab(const _Float16* __restrict__ slabs,
                                                     const unsigned* __restrict__ frecs,
                                                     const int* __restrict__ rs,
                                                     const int* __restrict__ re,
                                                     const float* __restrict__ bias,
                                                     float* __restrict__ out,
                                                     int N) {
    const int tid = threadIdx.x;
    const int b = blockIdx.x >> 3;
    const int g = blockIdx.x & 7;
    const int wv = tid >> 6;
    const int lane = tid & 63;
    const int eslot = lane >> 3;
    const int fpair = lane & 7;
    const _Float16* slab = slabs + (size_t)g * N * 16;
    const int row0 = (b << 7) + wv * 32;

    float2 bb = *(const float2*)(bias + g * 16 + fpair * 2);

    for (int rrow = 0; rrow < 32; ++rrow) {
        int r = row0 + rrow;
        if (r >= N) break;
        int s = rs[r], e = re[r];

        float ax = 0.f, ay = 0.f;
        for (int i = s + eslot; i < e; i += 8) {
            unsigned rec = frecs[i];
            float v = f16val15(rec);
            unsigned c = rec >> 15;
            half2v h = *(const half2v*)(slab + (size_t)c * 16 + fpair * 2);
            ax += v * (float)h.x;
            ay += v * (float)h.y;
        }
        // fold 8 eslot partials -> lanes 0..7 (one per fpair)
        ax += __shfl_down(ax, 32); ay += __shfl_down(ay, 32);
        ax += __shfl_down(ax, 16); ay += __shfl_down(ay, 16);
        ax += __shfl_down(ax, 8);  ay += __shfl_down(ay, 8);
        if (eslot == 0) {
            float2 o;
            o.x = ax + bb.x;
            o.y = ay + bb.y;
            *(float2*)(out + (size_t)r * OUTF + g * 16 + fpair * 2) = o;
        }
    }
}

// ---------------------------------------------------------------------------
extern "C" void kernel_launch(void* const* d_in, const int* in_sizes, int n_in,
                              void* d_out, int out_size, void* d_ws, size_t ws_size,
                              hipStream_t stream) {
    const float* x    = (const float*)d_in[0];
    const float* vals = (const float*)d_in[1];
    const float* w    = (const float*)d_in[2];
    const float* bias = (const float*)d_in[3];
    const int*   row  = (const int*)d_in[4];
    const int*   col  = (const int*)d_in[5];

    const int N = in_sizes[0] / INF;   // 100000
    const int E = in_sizes[1];         // 3200000
    const int NB = (N + 127) / 128;    // 782 coarse buckets

    // ---- workspace carve-up ----
    char* p = (char*)d_ws;
    _Float16* support = (_Float16*)p;  p += (size_t)N * OUTF * sizeof(_Float16);        // 25.6 MB
    unsigned* frecs   = (unsigned*)p;  p += (size_t)NB * BUCKET_CAP * sizeof(unsigned); // 14.4 MB
    _Float16* wpack   = (_Float16*)p;  p += (size_t)INF * OUTF * sizeof(_Float16);      // 64 KB
    int* rs           = (int*)p;       p += (size_t)N * sizeof(int);
    int* re           = (int*)p;       p += (size_t)N * sizeof(int);
    int* bcursor      = (int*)p;       p += (size_t)NBMAX * sizeof(int);

    // d_out (51.2 MB) doubles as coarse-partition scratch:
    // cv_tmp (14.4 MB) + lr_tmp (3.6 MB); gather fully overwrites it after.
    unsigned* cv_tmp      = (unsigned*)d_out;
    unsigned char* lr_tmp = (unsigned char*)d_out + (size_t)NB * BUCKET_CAP * sizeof(unsigned);

    const int eb4096 = (E + 4095) / 4096;

    // 1) prepack W (f16 B-frag layout) + init bucket cursors
    k_prepack<<<(INF * OUTF) / 256, 256, 0, stream>>>(w, wpack, bcursor, NB);

    // 2) GEMM: support slabs = x @ w  via f16 MFMA
    gcn_gemm_mfma<<<(N + 127) / 128, 256, 0, stream>>>(x, wpack, support, N);

    // 3) partition edges into fixed-capacity coarse buckets
    k_coarse_scatter<<<eb4096, 256, 0, stream>>>(row, col, vals, bcursor,
                                                 cv_tmp, lr_tmp, NB, E);

    // 4) per-bucket counting sort -> per-row-ordered records + rs/re
    k_bucket_sort<<<NB, 256, 0, stream>>>(cv_tmp, lr_tmp, bcursor, frecs, rs, re, N);

    // 5) gather: (bucket, slab) blocks, register accumulation, bias fused
    k_gather_slab<<<NB * 8, 256, 0, stream>>>(support, frecs, rs, re, bias,
                                              (float*)d_out, N);
}

// Round 7
// 419.049 us; speedup vs baseline: 5.6370x; 1.5129x over previous
//
#include <hip/hip_runtime.h>

#define INF 256
#define OUTF 128
#define NBMAX 1024        // max coarse buckets (row>>7 -> 782 for N=100000)
#define BUCKET_CAP 4608   // per-bucket capacity: mean 4092, std 64 -> +8 sigma

typedef _Float16 half2v __attribute__((ext_vector_type(2)));
typedef _Float16 half8 __attribute__((ext_vector_type(8)));
typedef float f32x4 __attribute__((ext_vector_type(4)));

__device__ inline unsigned short f16bits(float v) {
    union { unsigned short u; _Float16 h; } cv;
    cv.h = (_Float16)v;
    return cv.u;
}
__device__ inline float f16val15(unsigned rec) {
    union { unsigned short u; _Float16 h; } cv;
    cv.u = (unsigned short)(rec << 1);
    return (float)cv.h;
}

// ---------------------------------------------------------------------------
// Prepack W into MFMA B-fragment order (f16) + init bucket cursors.
// ---------------------------------------------------------------------------
__global__ __launch_bounds__(256) void k_prepack(const float* __restrict__ w,
                                                 _Float16* __restrict__ wpack,
                                                 int* __restrict__ bcursor,
                                                 int NB) {
    int t = blockIdx.x * 256 + threadIdx.x;   // 32768 threads
    int k = t >> 7, n = t & 127;
    int ks = k >> 5, quad = (k >> 3) & 3, j = k & 7;
    int ct = n >> 4, nn = n & 15;
    wpack[(((ks * 8 + ct) * 4 + quad) * 16 + nn) * 8 + j] = (_Float16)w[k * OUTF + n];
    if (t < NB) bcursor[t] = t * BUCKET_CAP;
}

// ---------------------------------------------------------------------------
// MFMA GEMM: support(f16, row-major) = x(f32) @ w, 16x16x32 f16 MFMA, no LDS.
// 64 rows/block (wave = 16 rows) -> 1563 blocks, 6 waves/SIMD for latency
// hiding of the x loads. acc = 32 VGPR/wave.
// ---------------------------------------------------------------------------
__global__ __launch_bounds__(256) void gcn_gemm_mfma(const float* __restrict__ x,
                                                     const _Float16* __restrict__ wpack,
                                                     _Float16* __restrict__ support,
                                                     int N) {
    const int tid = threadIdx.x;
    const int wv = tid >> 6;
    const int lane = tid & 63;
    const int m16 = lane & 15;
    const int quad = lane >> 4;
    const int rowbase = blockIdx.x * 64 + wv * 16;

    f32x4 acc[8];
#pragma unroll
    for (int ct = 0; ct < 8; ++ct)
        acc[ct] = (f32x4){0.f, 0.f, 0.f, 0.f};

    int r0 = rowbase + m16;
    int r0c = (r0 < N) ? r0 : N - 1;   // clamp (dup read, store-guarded)
    const float* xr0 = x + (long)r0c * INF + quad * 8;

    for (int ks = 0; ks < 8; ++ks) {
        float4 u0 = *(const float4*)(xr0 + ks * 32);
        float4 v0 = *(const float4*)(xr0 + ks * 32 + 4);
        half8 a0 = {(_Float16)u0.x, (_Float16)u0.y, (_Float16)u0.z, (_Float16)u0.w,
                    (_Float16)v0.x, (_Float16)v0.y, (_Float16)v0.z, (_Float16)v0.w};

        half8 b[8];
#pragma unroll
        for (int ct = 0; ct < 8; ++ct)
            b[ct] = *(const half8*)(wpack + (size_t)(((ks * 8 + ct) * 4 + quad) * 16 + m16) * 8);

#pragma unroll
        for (int ct = 0; ct < 8; ++ct)
            acc[ct] = __builtin_amdgcn_mfma_f32_16x16x32_f16(a0, b[ct], acc[ct], 0, 0, 0);
    }

    // C/D layout: col = lane&15, row = quad*4 + reg. Row-major store.
    int rb = rowbase + quad * 4;
#pragma unroll
    for (int reg = 0; reg < 4; ++reg) {
        int r = rb + reg;
        if (r < N) {
#pragma unroll
            for (int ct = 0; ct < 8; ++ct)
                support[(long)r * OUTF + ct * 16 + m16] = (_Float16)acc[ct][reg];
        }
    }
}

// ---------------------------------------------------------------------------
// Coarse scatter: append final-format records into fixed-capacity buckets.
// cv_tmp[pos] = col<<15 | f16(val)>>1 (4B), lr_tmp[pos] = row&127 (1B).
// ---------------------------------------------------------------------------
__global__ __launch_bounds__(256) void k_coarse_scatter(const int* __restrict__ row,
                                                        const int* __restrict__ col,
                                                        const float* __restrict__ vals,
                                                        int* __restrict__ bcursor,
                                                        unsigned* __restrict__ cv_tmp,
                                                        unsigned char* __restrict__ lr_tmp,
                                                        int NB, int E) {
    __shared__ int cnt[NBMAX];
    __shared__ int sbase[NBMAX];
    const int tid = threadIdx.x;
    for (int i = tid; i < NB; i += 256) cnt[i] = 0;
    __syncthreads();

    int rr[16], rk[16];
    unsigned rec[16];
    int base = blockIdx.x * 4096;
#pragma unroll
    for (int j = 0; j < 16; ++j) {
        int e = base + j * 256 + tid;
        if (e < E) {
            int r = row[e];
            rec[j] = ((unsigned)col[e] << 15) | ((unsigned)f16bits(vals[e]) >> 1);
            rr[j] = r;
            rk[j] = atomicAdd(&cnt[r >> 7], 1);
        } else {
            rr[j] = -1;
        }
    }
    __syncthreads();
    for (int i = tid; i < NB; i += 256) {
        int c = cnt[i];
        if (c) sbase[i] = atomicAdd(&bcursor[i], c);
    }
    __syncthreads();
#pragma unroll
    for (int j = 0; j < 16; ++j) {
        if (rr[j] >= 0) {
            int pos = sbase[rr[j] >> 7] + rk[j];
            cv_tmp[pos] = rec[j];
            lr_tmp[pos] = (unsigned char)(rr[j] & 127);
        }
    }
}

// ---------------------------------------------------------------------------
// Per-bucket counting sort: permute 4B records into per-row order + rs/re.
// ---------------------------------------------------------------------------
__global__ __launch_bounds__(256) void k_bucket_sort(const unsigned* __restrict__ cv_tmp,
                                                     const unsigned char* __restrict__ lr_tmp,
                                                     const int* __restrict__ bcursor,
                                                     unsigned* __restrict__ frecs,
                                                     int* __restrict__ rs,
                                                     int* __restrict__ re,
                                                     int N) {
    __shared__ unsigned recs[BUCKET_CAP];
    __shared__ unsigned char lrows[BUCKET_CAP];
    __shared__ int cnt[128];
    __shared__ int offs[128];

    const int tid = threadIdx.x;
    const int b = blockIdx.x;
    const int start = b * BUCKET_CAP;
    int n = bcursor[b] - start;
    if (n > BUCKET_CAP) n = BUCKET_CAP;
    const int row0 = b << 7;

    if (tid < 128) cnt[tid] = 0;
    __syncthreads();

    for (int i = tid; i < n; i += 256) {
        unsigned c = cv_tmp[start + i];
        unsigned char l = lr_tmp[start + i];
        recs[i] = c;
        lrows[i] = l;
        atomicAdd(&cnt[l], 1);
    }
    __syncthreads();

    if (tid < 128) offs[tid] = cnt[tid];
    __syncthreads();
    for (int d = 1; d < 128; d <<= 1) {
        int add = 0;
        if (tid < 128 && tid >= d) add = offs[tid - d];
        __syncthreads();
        if (tid < 128) offs[tid] += add;
        __syncthreads();
    }
    if (tid < 128) {
        int excl = offs[tid] - cnt[tid];
        offs[tid] = excl;                 // running cursor
        int r = row0 + tid;
        if (r < N) {
            rs[r] = start + excl;
            re[r] = start + excl + cnt[tid];
        }
    }
    __syncthreads();

    for (int i = tid; i < n; i += 256) {
        int l = lrows[i];
        int pos = atomicAdd(&offs[l], 1);
        frecs[start + pos] = recs[i];
    }
}

// ---------------------------------------------------------------------------
// Gather: one wave per destination row; lane owns 2 features (f16x2 loads).
// 8-deep unroll -> 8 independent support loads in flight per lane.
// ---------------------------------------------------------------------------
__global__ __launch_bounds__(256) void k_gather(const half2v* __restrict__ sup,
                                                const unsigned* __restrict__ frecs,
                                                const int* __restrict__ rs,
                                                const int* __restrict__ re,
                                                const float* __restrict__ bias,
                                                float* __restrict__ out,
                                                int N) {
    int wid = (blockIdx.x * 256 + threadIdx.x) >> 6;
    int lane = threadIdx.x & 63;
    if (wid >= N) return;

    int s = rs[wid];
    int e = re[wid];

    float ax = 0.f, ay = 0.f;
    int i = s;
    for (; i + 8 <= e; i += 8) {
        unsigned r[8];
        half2v h[8];
#pragma unroll
        for (int j = 0; j < 8; ++j) r[j] = frecs[i + j];
#pragma unroll
        for (int j = 0; j < 8; ++j) h[j] = sup[(size_t)(r[j] >> 15) * 64 + lane];
#pragma unroll
        for (int j = 0; j < 8; ++j) {
            float v = f16val15(r[j]);
            ax += v * (float)h[j].x;
            ay += v * (float)h[j].y;
        }
    }
    for (; i < e; ++i) {
        unsigned r = frecs[i];
        float v = f16val15(r);
        half2v h = sup[(size_t)(r >> 15) * 64 + lane];
        ax += v * (float)h.x;
        ay += v * (float)h.y;
    }

    float2 bb = ((const float2*)bias)[lane];
    float2 o;
    o.x = ax + bb.x;
    o.y = ay + bb.y;
    ((float2*)out)[(size_t)wid * 64 + lane] = o;
}

// ---------------------------------------------------------------------------
extern "C" void kernel_launch(void* const* d_in, const int* in_sizes, int n_in,
                              void* d_out, int out_size, void* d_ws, size_t ws_size,
                              hipStream_t stream) {
    const float* x    = (const float*)d_in[0];
    const float* vals = (const float*)d_in[1];
    const float* w    = (const float*)d_in[2];
    const float* bias = (const float*)d_in[3];
    const int*   row  = (const int*)d_in[4];
    const int*   col  = (const int*)d_in[5];

    const int N = in_sizes[0] / INF;   // 100000
    const int E = in_sizes[1];         // 3200000
    const int NB = (N + 127) / 128;    // 782 coarse buckets

    // ---- workspace carve-up ----
    char* p = (char*)d_ws;
    _Float16* support = (_Float16*)p;  p += (size_t)N * OUTF * sizeof(_Float16);        // 25.6 MB
    unsigned* frecs   = (unsigned*)p;  p += (size_t)NB * BUCKET_CAP * sizeof(unsigned); // 14.4 MB
    _Float16* wpack   = (_Float16*)p;  p += (size_t)INF * OUTF * sizeof(_Float16);      // 64 KB
    int* rs           = (int*)p;       p += (size_t)N * sizeof(int);
    int* re           = (int*)p;       p += (size_t)N * sizeof(int);
    int* bcursor      = (int*)p;       p += (size_t)NBMAX * sizeof(int);

    // d_out (51.2 MB) doubles as coarse-partition scratch:
    // cv_tmp (14.4 MB) + lr_tmp (3.6 MB); gather fully overwrites it after.
    unsigned* cv_tmp      = (unsigned*)d_out;
    unsigned char* lr_tmp = (unsigned char*)d_out + (size_t)NB * BUCKET_CAP * sizeof(unsigned);

    const int eb4096 = (E + 4095) / 4096;

    // 1) prepack W (f16 B-frag layout) + init bucket cursors
    k_prepack<<<(INF * OUTF) / 256, 256, 0, stream>>>(w, wpack, bcursor, NB);

    // 2) GEMM: support = x @ w  via f16 MFMA (64-row blocks, 6 waves/SIMD)
    gcn_gemm_mfma<<<(N + 63) / 64, 256, 0, stream>>>(x, wpack, support, N);

    // 3) partition edges into fixed-capacity coarse buckets
    k_coarse_scatter<<<eb4096, 256, 0, stream>>>(row, col, vals, bcursor,
                                                 cv_tmp, lr_tmp, NB, E);

    // 4) per-bucket counting sort -> per-row-ordered records + rs/re
    k_bucket_sort<<<NB, 256, 0, stream>>>(cv_tmp, lr_tmp, bcursor, frecs, rs, re, N);

    // 5) gather: one wave per row, 8-deep unroll, bias fused
    {
        int blocks = (N * 64 + 255) / 256;
        k_gather<<<blocks, 256, 0, stream>>>((const half2v*)support, frecs,
                                             rs, re, bias, (float*)d_out, N);
    }
}